// Round 10
// baseline (178.663 us; speedup 1.0000x reference)
//
#include <hip/hip_runtime.h>

#define N_USER 50000
#define N_ITEM 50000
#define N_EDGE 800000
#define D 128
#define NTOT   100000          // combined dst space: [0,50K)=items, [50K,100K)=users
#define NE2    1600000         // both directions' edges
#define BKT_SH 9               // 512 dsts per bucket
#define NBKT   196             // ceil(NTOT / 512)
#define CAP    12288           // LDS csr staging cap (bucket mean 8192, sigma ~90)

typedef __attribute__((ext_vector_type(8))) short     bf16x8;
typedef __attribute__((ext_vector_type(4))) float     f32x4;
typedef __attribute__((ext_vector_type(4))) unsigned short ushortx4;
typedef __attribute__((ext_vector_type(8))) unsigned short ushortx8;

__device__ __forceinline__ unsigned short f2bf(float f) {
    unsigned int u = __float_as_uint(f);
    unsigned int r = (u + 0x7fffu + ((u >> 16) & 1u)) >> 16;   // RNE
    return (unsigned short)r;
}
__device__ __forceinline__ float bf2f(unsigned short b) {
    return __uint_as_float(((unsigned int)b) << 16);
}

// ---------------------------------------------------------------------------
// Bucket-count: LDS-binned count of 1.6M edge dsts -> gcnt[196]
// ---------------------------------------------------------------------------
#define CNT_BLOCKS 391   // ceil(NE2 / 4096)

__global__ __launch_bounds__(256) void count_kernel(
    const int* __restrict__ edge_ui, const int* __restrict__ edge_iu,
    int* __restrict__ gcnt)
{
    __shared__ int bcnt[NBKT];
    const int tid = threadIdx.x;
    for (int i = tid; i < NBKT; i += 256) bcnt[i] = 0;
    __syncthreads();
    int e0 = blockIdx.x * 4096;
#pragma unroll
    for (int j = 0; j < 16; ++j) {
        int e = e0 + j * 256 + tid;
        if (e < NE2) {
            int d = (e < N_EDGE) ? edge_ui[N_EDGE + e]
                                 : (N_ITEM + edge_iu[N_EDGE + (e - N_EDGE)]);
            atomicAdd(&bcnt[d >> BKT_SH], 1);
        }
    }
    __syncthreads();
    for (int i = tid; i < NBKT; i += 256)
        if (bcnt[i]) atomicAdd(&gcnt[i], bcnt[i]);
}

// ---------------------------------------------------------------------------
// Scan 196 bucket counts -> bucket bases; init bucket cursors.
// ---------------------------------------------------------------------------
__global__ __launch_bounds__(256) void bucketscan_kernel(
    const int* __restrict__ gcnt, int* __restrict__ bbase, int* __restrict__ bcur)
{
    __shared__ int s[256];
    int tid = threadIdx.x;
    int v = (tid < NBKT) ? gcnt[tid] : 0;
    s[tid] = v;
    __syncthreads();
    for (int d = 1; d < 256; d <<= 1) {
        int t = (tid >= d) ? s[tid - d] : 0;
        __syncthreads();
        s[tid] += t;
        __syncthreads();
    }
    if (tid < NBKT) {
        int base = s[tid] - v;     // exclusive
        bbase[tid] = base;
        bcur[tid]  = base;
    }
    if (tid == NBKT - 1) bbase[NBKT] = s[tid];
}

// ---------------------------------------------------------------------------
// MEGA kernel (block-range roles, all 256 thr):
//  [0, 12500)          pack features -> compact bf16 tables T_user/T_item
//  [12500, 12532)      pack W frags (2 x 4096 ids)
//  [12532, 13316)      scatter records (rank-capture, 8 edges/thread)
// Record = src16 | dstlow9<<16.
// ---------------------------------------------------------------------------
#define PACKA_BLOCKS 12500
#define PACKW_BLOCKS 32
#define SCAT_BLOCKS  784   // ceil(NE2 / 2048)

__global__ __launch_bounds__(256) void mega2_kernel(
    const float* __restrict__ user_emb, const int* __restrict__ user_ids,
    const float* __restrict__ item_x,
    const int* __restrict__ edge_ui, const int* __restrict__ edge_iu,
    const float* __restrict__ Wl_ui, const float* __restrict__ Wr_ui,
    const float* __restrict__ Wl_iu, const float* __restrict__ Wr_iu,
    unsigned short* T_user, unsigned short* T_item,
    unsigned short* WfragUI, unsigned short* WfragIU,
    int* __restrict__ bcur, unsigned int* __restrict__ records)
{
    const int b = blockIdx.x;
    const int tid = threadIdx.x;

    if (b < PACKA_BLOCKS) {
        int gid = b * 256 + tid;
        int row = gid >> 5;
        int c = (gid & 31) << 2;
        const float* src;
        unsigned short* dst;
        if (row < N_USER) {
            src = user_emb + (size_t)user_ids[row] * D;
            dst = T_user + (size_t)row * 128;
        } else {
            int r = row - N_USER;
            src = item_x + (size_t)r * D;
            dst = T_item + (size_t)r * 128;
        }
        const float4 v = *reinterpret_cast<const float4*>(src + c);
        ushortx4 o;
        o.x = f2bf(v.x); o.y = f2bf(v.y); o.z = f2bf(v.z); o.w = f2bf(v.w);
        *reinterpret_cast<ushortx4*>(dst + c) = o;
    } else if (b < PACKA_BLOCKS + PACKW_BLOCKS) {
        int id = (b - PACKA_BLOCKS) * 256 + tid;   // [0, 8192)
        const float *Wl, *Wr;
        unsigned short* Wf;
        if (id < 4096) { Wl = Wl_ui; Wr = Wr_ui; Wf = WfragUI; }
        else { id -= 4096; Wl = Wl_iu; Wr = Wr_iu; Wf = WfragIU; }
        int lane = id & 63;
        int c    = (id >> 6) & 7;
        int ks   = id >> 9;
        int col  = c * 16 + (lane & 15);
        int k0   = ks * 32 + (lane >> 4) * 8;
        ushortx8 o;
#pragma unroll
        for (int i = 0; i < 8; ++i) {
            int k = k0 + i;
            float f = (k < D) ? Wl[(size_t)k * D + col] : Wr[(size_t)(k - D) * D + col];
            o[i] = f2bf(f);
        }
        *reinterpret_cast<ushortx8*>(Wf + (size_t)id * 8) = o;
    } else {
        __shared__ int bcnt[NBKT];
        __shared__ int bpos[NBKT];
        for (int i = tid; i < NBKT; i += 256) bcnt[i] = 0;
        __syncthreads();

        const int e0 = (b - PACKA_BLOCKS - PACKW_BLOCKS) * 2048;
        unsigned int rec[8];
        int bkt[8], rnk[8];
#pragma unroll
        for (int j = 0; j < 8; ++j) {
            int e = e0 + j * 256 + tid;
            bkt[j] = -1;
            if (e < NE2) {
                int s, d;
                if (e < N_EDGE) { s = edge_ui[e]; d = edge_ui[N_EDGE + e]; }
                else { int f = e - N_EDGE; s = edge_iu[f]; d = N_ITEM + edge_iu[N_EDGE + f]; }
                bkt[j] = d >> BKT_SH;
                rec[j] = (unsigned int)s | ((unsigned int)(d & 511) << 16);
                rnk[j] = atomicAdd(&bcnt[bkt[j]], 1);
            }
        }
        __syncthreads();
        for (int i = tid; i < NBKT; i += 256) {
            int c = bcnt[i];
            bpos[i] = c ? atomicAdd(&bcur[i], c) : 0;
        }
        __syncthreads();
#pragma unroll
        for (int j = 0; j < 8; ++j) {
            if (bkt[j] >= 0) records[bpos[bkt[j]] + rnk[j]] = rec[j];
        }
    }
}

// ---------------------------------------------------------------------------
// Per-bucket CSR build: LDS counting-sort by dst within the bucket; emits off[].
// ---------------------------------------------------------------------------
__global__ __launch_bounds__(1024) void csr_build_kernel(
    const unsigned int* __restrict__ records, const int* __restrict__ bbase,
    unsigned short* __restrict__ csr, int* __restrict__ off)
{
    __shared__ int dcnt[512];
    __shared__ int sa[512], sb[512];
    __shared__ int dcur[512];
    __shared__ unsigned short stage[CAP];

    const int b    = blockIdx.x;
    const int tid  = threadIdx.x;
    const int base = bbase[b];
    const int nb   = bbase[b + 1] - base;

    if (tid < 512) dcnt[tid] = 0;
    __syncthreads();

    for (int i = tid; i < nb; i += 1024)
        atomicAdd(&dcnt[records[base + i] >> 16], 1);
    __syncthreads();

    int* pa = sa; int* pb = sb;
    if (tid < 512) pa[tid] = dcnt[tid];
    __syncthreads();
    for (int d = 1; d < 512; d <<= 1) {
        if (tid < 512) pb[tid] = pa[tid] + ((tid >= d) ? pa[tid - d] : 0);
        __syncthreads();
        int* t = pa; pa = pb; pb = t;
    }
    if (tid < 512) {
        int excl = pa[tid] - dcnt[tid];
        dcur[tid] = excl;
        int dst = b * 512 + tid;
        if (dst < NTOT) off[dst] = base + excl;
    }
    if (b == NBKT - 1 && tid == 0) off[NTOT] = NE2;
    __syncthreads();

    if (nb <= CAP) {
        for (int i = tid; i < nb; i += 1024) {
            unsigned int r = records[base + i];
            int p = atomicAdd(&dcur[r >> 16], 1);
            stage[p] = (unsigned short)r;
        }
        __syncthreads();
        for (int i = tid; i < nb; i += 1024) csr[base + i] = stage[i];
    } else {
        for (int i = tid; i < nb; i += 1024) {
            unsigned int r = records[base + i];
            int p = atomicAdd(&dcur[r >> 16], 1);
            csr[base + p] = (unsigned short)r;
        }
    }
}

// ---------------------------------------------------------------------------
// FUSED aggregate + MFMA finish, v3: ONE ROW PER WAVE (agg2's decomposition).
// Block = 1024 thr = 16 waves, owns 16 output rows of one side (50000 = 3125*16,
// no bounds checks).
//  phase 1: wave w aggregates row rowBase+w exactly like agg2 (lane owns dims
//           [2l,2l+1], 4 independent gathers in flight), mean -> hd[w][*].
//  phase 2: waves 0-7 (cg = wave): 16x16 output tile col-group, 8 k-steps;
//           A head from LDS, tail from Ts; waves 8-15 exit after barrier.
// ---------------------------------------------------------------------------
#define BLK_SIDE 3125   // 50000 / 16

__global__ __launch_bounds__(1024, 8) void aggfin3_kernel(
    const unsigned short* __restrict__ T_user, const unsigned short* __restrict__ T_item,
    const int* __restrict__ off, const unsigned short* __restrict__ csr,
    const unsigned short* __restrict__ WfragUI, const unsigned short* __restrict__ WfragIU,
    const float* __restrict__ b_ui, const float* __restrict__ b_iu,
    float* out_item, float* out_user)
{
    __shared__ unsigned short hd[16][136];   // head tile (16B-aligned rows)

    const int b = blockIdx.x;
    const unsigned short *Tg, *Ts, *Wfrag;
    const float* bias;
    float* outp;
    int rowBase, dstOfs;
    if (b < BLK_SIDE) {
        // item side: aggregate USER features, self = ITEM features
        Tg = T_user; Ts = T_item; Wfrag = WfragUI; bias = b_ui;
        outp = out_item; rowBase = b * 16; dstOfs = 0;
    } else {
        // user side: aggregate ITEM features, self = USER features
        Tg = T_item; Ts = T_user; Wfrag = WfragIU; bias = b_iu;
        outp = out_user; rowBase = (b - BLK_SIDE) * 16; dstOfs = N_ITEM;
    }

    const int tid  = threadIdx.x;
    const int wave = tid >> 6;       // 0..15
    const int lane = tid & 63;

    // ---- phase 1: aggregation, ONE row per wave ----
    {
        const int co  = lane * 2;
        const int dr  = dstOfs + rowBase + wave;
        const int o0  = off[dr], o1 = off[dr + 1];
        const int deg = o1 - o0;
        float ax = 0.f, ay = 0.f;
        int i = o0;
        for (; i + 3 < o1; i += 4) {
            int s0 = csr[i], s1 = csr[i + 1], s2 = csr[i + 2], s3 = csr[i + 3];
            unsigned int w0 = *reinterpret_cast<const unsigned int*>(Tg + (size_t)s0 * 128 + co);
            unsigned int w1 = *reinterpret_cast<const unsigned int*>(Tg + (size_t)s1 * 128 + co);
            unsigned int w2 = *reinterpret_cast<const unsigned int*>(Tg + (size_t)s2 * 128 + co);
            unsigned int w3 = *reinterpret_cast<const unsigned int*>(Tg + (size_t)s3 * 128 + co);
            ax += bf2f((unsigned short)w0) + bf2f((unsigned short)w1)
                + bf2f((unsigned short)w2) + bf2f((unsigned short)w3);
            ay += bf2f((unsigned short)(w0 >> 16)) + bf2f((unsigned short)(w1 >> 16))
                + bf2f((unsigned short)(w2 >> 16)) + bf2f((unsigned short)(w3 >> 16));
        }
        for (; i < o1; ++i) {
            int s = csr[i];
            unsigned int w = *reinterpret_cast<const unsigned int*>(Tg + (size_t)s * 128 + co);
            ax += bf2f((unsigned short)w);
            ay += bf2f((unsigned short)(w >> 16));
        }
        float sc = (deg > 0) ? 1.0f / (float)deg : 0.0f;
        unsigned int outw = (unsigned int)f2bf(ax * sc) | ((unsigned int)f2bf(ay * sc) << 16);
        *reinterpret_cast<unsigned int*>(&hd[wave][co]) = outw;
    }
    __syncthreads();

    // ---- phase 2: MFMA, waves 0-7 only (cg = wave) ----
    if (wave >= 8) return;
    const int cg = wave;
    const int kg = lane >> 4;
    const int r16 = lane & 15;
    const unsigned short* tail_ptr = Ts + (size_t)(rowBase + r16) * 128 + kg * 8;  // SELF
    const unsigned short* hrow = &hd[r16][kg * 8];

    f32x4 acc = (f32x4){0.f, 0.f, 0.f, 0.f};
#pragma unroll
    for (int ks = 0; ks < 8; ++ks) {
        bf16x8 a;
        if (ks < 4) a = *reinterpret_cast<const bf16x8*>(hrow + ks * 32);           // agg (Wl)
        else        a = *reinterpret_cast<const bf16x8*>(tail_ptr + (ks - 4) * 32); // self (Wr)
        bf16x8 bb = *reinterpret_cast<const bf16x8*>(Wfrag + ((size_t)(ks * 8 + cg) * 64 + lane) * 8);
        acc = __builtin_amdgcn_mfma_f32_16x16x32_bf16(a, bb, acc, 0, 0, 0);
    }

    const int ocol = cg * 16 + r16;
    const float bv = bias[ocol];
    const int orow0 = rowBase + kg * 4;
#pragma unroll
    for (int r = 0; r < 4; ++r)
        outp[(size_t)(orow0 + r) * 128 + ocol] = acc[r] + bv;
}

// ---------------------------------------------------------------------------
extern "C" void kernel_launch(void* const* d_in, const int* in_sizes, int n_in,
                              void* d_out, int out_size, void* d_ws, size_t ws_size,
                              hipStream_t stream) {
    const int*   user_ids = (const int*)d_in[0];
    const float* item_x   = (const float*)d_in[1];
    const int*   edge_ui  = (const int*)d_in[2];
    const int*   edge_iu  = (const int*)d_in[3];
    const float* user_emb = (const float*)d_in[4];
    const float* W_l_ui   = (const float*)d_in[5];
    const float* W_r_ui   = (const float*)d_in[6];
    const float* b_ui     = (const float*)d_in[7];
    const float* W_l_iu   = (const float*)d_in[8];
    const float* W_r_iu   = (const float*)d_in[9];
    const float* b_iu     = (const float*)d_in[10];

    float* out_user = (float*)d_out;
    float* out_item = out_user + (size_t)N_USER * D;

    // Workspace (16B-aligned blocks first)
    unsigned short* WfragUI = (unsigned short*)d_ws;            // 32768 u16
    unsigned short* WfragIU = WfragUI + 32768;                  // 32768 u16
    unsigned short* T_user  = WfragIU + 32768;                  // 50000*128 u16 (12.8MB)
    unsigned short* T_item  = T_user + (size_t)N_USER * 128;    // 12.8MB
    unsigned int*   records = (unsigned int*)(T_item + (size_t)N_ITEM * 128);  // NE2 (6.4MB)
    unsigned short* csr     = (unsigned short*)(records + NE2); // NE2 (3.2MB)
    int* gcnt  = (int*)(csr + NE2);                             // NBKT
    int* bbase = gcnt + NBKT;                                   // NBKT+1
    int* bcur  = bbase + NBKT + 1;                              // NBKT
    int* off   = bcur + NBKT;                                   // NTOT+1

    hipMemsetAsync(gcnt, 0, NBKT * sizeof(int), stream);

    count_kernel<<<CNT_BLOCKS, 256, 0, stream>>>(edge_ui, edge_iu, gcnt);
    bucketscan_kernel<<<1, 256, 0, stream>>>(gcnt, bbase, bcur);
    mega2_kernel<<<PACKA_BLOCKS + PACKW_BLOCKS + SCAT_BLOCKS, 256, 0, stream>>>(
        user_emb, user_ids, item_x, edge_ui, edge_iu,
        W_l_ui, W_r_ui, W_l_iu, W_r_iu,
        T_user, T_item, WfragUI, WfragIU, bcur, records);
    csr_build_kernel<<<NBKT, 1024, 0, stream>>>(records, bbase, csr, off);

    aggfin3_kernel<<<2 * BLK_SIDE, 1024, 0, stream>>>(
        T_user, T_item, off, csr, WfragUI, WfragIU, b_ui, b_iu, out_item, out_user);
}

// Round 11
// 169.518 us; speedup vs baseline: 1.0539x; 1.0539x over previous
//
#include <hip/hip_runtime.h>

#define N_USER 50000
#define N_ITEM 50000
#define N_EDGE 800000
#define D 128
#define NTOT   100000          // combined dst space: [0,50K)=items, [50K,100K)=users
#define NE2    1600000         // both directions' edges
#define BKT_SH 9               // 512 dsts per bucket
#define NBKT   196             // ceil(NTOT / 512)
#define CAP    12288           // LDS csr staging cap (bucket mean 8192, sigma ~90)

typedef __attribute__((ext_vector_type(8))) short     bf16x8;
typedef __attribute__((ext_vector_type(4))) float     f32x4;
typedef __attribute__((ext_vector_type(4))) unsigned short ushortx4;
typedef __attribute__((ext_vector_type(8))) unsigned short ushortx8;

__device__ __forceinline__ unsigned short f2bf(float f) {
    unsigned int u = __float_as_uint(f);
    unsigned int r = (u + 0x7fffu + ((u >> 16) & 1u)) >> 16;   // RNE
    return (unsigned short)r;
}
__device__ __forceinline__ float bf2f(unsigned short b) {
    return __uint_as_float(((unsigned int)b) << 16);
}

// ---------------------------------------------------------------------------
// Bucket-count: LDS-binned count of 1.6M edge dsts -> gcnt[196]
// ---------------------------------------------------------------------------
#define CNT_BLOCKS 391   // ceil(NE2 / 4096)

__global__ __launch_bounds__(256) void count_kernel(
    const int* __restrict__ edge_ui, const int* __restrict__ edge_iu,
    int* __restrict__ gcnt)
{
    __shared__ int bcnt[NBKT];
    const int tid = threadIdx.x;
    for (int i = tid; i < NBKT; i += 256) bcnt[i] = 0;
    __syncthreads();
    int e0 = blockIdx.x * 4096;
#pragma unroll
    for (int j = 0; j < 16; ++j) {
        int e = e0 + j * 256 + tid;
        if (e < NE2) {
            int d = (e < N_EDGE) ? edge_ui[N_EDGE + e]
                                 : (N_ITEM + edge_iu[N_EDGE + (e - N_EDGE)]);
            atomicAdd(&bcnt[d >> BKT_SH], 1);
        }
    }
    __syncthreads();
    for (int i = tid; i < NBKT; i += 256)
        if (bcnt[i]) atomicAdd(&gcnt[i], bcnt[i]);
}

// ---------------------------------------------------------------------------
// Scan 196 bucket counts -> bucket bases; init bucket cursors.
// ---------------------------------------------------------------------------
__global__ __launch_bounds__(256) void bucketscan_kernel(
    const int* __restrict__ gcnt, int* __restrict__ bbase, int* __restrict__ bcur)
{
    __shared__ int s[256];
    int tid = threadIdx.x;
    int v = (tid < NBKT) ? gcnt[tid] : 0;
    s[tid] = v;
    __syncthreads();
    for (int d = 1; d < 256; d <<= 1) {
        int t = (tid >= d) ? s[tid - d] : 0;
        __syncthreads();
        s[tid] += t;
        __syncthreads();
    }
    if (tid < NBKT) {
        int base = s[tid] - v;     // exclusive
        bbase[tid] = base;
        bcur[tid]  = base;
    }
    if (tid == NBKT - 1) bbase[NBKT] = s[tid];
}

// ---------------------------------------------------------------------------
// MEGA kernel (block-range roles, all 256 thr):
//  [0, 12500)          pack features -> compact bf16 tables T_user/T_item
//  [12500, 12532)      pack W frags (2 x 4096 ids)
//  [12532, 13316)      scatter records (rank-capture, 8 edges/thread)
// Record = src16 | dstlow9<<16.
// ---------------------------------------------------------------------------
#define PACKA_BLOCKS 12500
#define PACKW_BLOCKS 32
#define SCAT_BLOCKS  784   // ceil(NE2 / 2048)

__global__ __launch_bounds__(256) void mega2_kernel(
    const float* __restrict__ user_emb, const int* __restrict__ user_ids,
    const float* __restrict__ item_x,
    const int* __restrict__ edge_ui, const int* __restrict__ edge_iu,
    const float* __restrict__ Wl_ui, const float* __restrict__ Wr_ui,
    const float* __restrict__ Wl_iu, const float* __restrict__ Wr_iu,
    unsigned short* T_user, unsigned short* T_item,
    unsigned short* WfragUI, unsigned short* WfragIU,
    int* __restrict__ bcur, unsigned int* __restrict__ records)
{
    const int b = blockIdx.x;
    const int tid = threadIdx.x;

    if (b < PACKA_BLOCKS) {
        int gid = b * 256 + tid;
        int row = gid >> 5;
        int c = (gid & 31) << 2;
        const float* src;
        unsigned short* dst;
        if (row < N_USER) {
            src = user_emb + (size_t)user_ids[row] * D;
            dst = T_user + (size_t)row * 128;
        } else {
            int r = row - N_USER;
            src = item_x + (size_t)r * D;
            dst = T_item + (size_t)r * 128;
        }
        const float4 v = *reinterpret_cast<const float4*>(src + c);
        ushortx4 o;
        o.x = f2bf(v.x); o.y = f2bf(v.y); o.z = f2bf(v.z); o.w = f2bf(v.w);
        *reinterpret_cast<ushortx4*>(dst + c) = o;
    } else if (b < PACKA_BLOCKS + PACKW_BLOCKS) {
        int id = (b - PACKA_BLOCKS) * 256 + tid;   // [0, 8192)
        const float *Wl, *Wr;
        unsigned short* Wf;
        if (id < 4096) { Wl = Wl_ui; Wr = Wr_ui; Wf = WfragUI; }
        else { id -= 4096; Wl = Wl_iu; Wr = Wr_iu; Wf = WfragIU; }
        int lane = id & 63;
        int c    = (id >> 6) & 7;
        int ks   = id >> 9;
        int col  = c * 16 + (lane & 15);
        int k0   = ks * 32 + (lane >> 4) * 8;
        ushortx8 o;
#pragma unroll
        for (int i = 0; i < 8; ++i) {
            int k = k0 + i;
            float f = (k < D) ? Wl[(size_t)k * D + col] : Wr[(size_t)(k - D) * D + col];
            o[i] = f2bf(f);
        }
        *reinterpret_cast<ushortx8*>(Wf + (size_t)id * 8) = o;
    } else {
        __shared__ int bcnt[NBKT];
        __shared__ int bpos[NBKT];
        for (int i = tid; i < NBKT; i += 256) bcnt[i] = 0;
        __syncthreads();

        const int e0 = (b - PACKA_BLOCKS - PACKW_BLOCKS) * 2048;
        unsigned int rec[8];
        int bkt[8], rnk[8];
#pragma unroll
        for (int j = 0; j < 8; ++j) {
            int e = e0 + j * 256 + tid;
            bkt[j] = -1;
            if (e < NE2) {
                int s, d;
                if (e < N_EDGE) { s = edge_ui[e]; d = edge_ui[N_EDGE + e]; }
                else { int f = e - N_EDGE; s = edge_iu[f]; d = N_ITEM + edge_iu[N_EDGE + f]; }
                bkt[j] = d >> BKT_SH;
                rec[j] = (unsigned int)s | ((unsigned int)(d & 511) << 16);
                rnk[j] = atomicAdd(&bcnt[bkt[j]], 1);
            }
        }
        __syncthreads();
        for (int i = tid; i < NBKT; i += 256) {
            int c = bcnt[i];
            bpos[i] = c ? atomicAdd(&bcur[i], c) : 0;
        }
        __syncthreads();
#pragma unroll
        for (int j = 0; j < 8; ++j) {
            if (bkt[j] >= 0) records[bpos[bkt[j]] + rnk[j]] = rec[j];
        }
    }
}

// ---------------------------------------------------------------------------
// Per-bucket CSR build: LDS counting-sort by dst within the bucket; emits off[].
// ---------------------------------------------------------------------------
__global__ __launch_bounds__(1024) void csr_build_kernel(
    const unsigned int* __restrict__ records, const int* __restrict__ bbase,
    unsigned short* __restrict__ csr, int* __restrict__ off)
{
    __shared__ int dcnt[512];
    __shared__ int sa[512], sb[512];
    __shared__ int dcur[512];
    __shared__ unsigned short stage[CAP];

    const int b    = blockIdx.x;
    const int tid  = threadIdx.x;
    const int base = bbase[b];
    const int nb   = bbase[b + 1] - base;

    if (tid < 512) dcnt[tid] = 0;
    __syncthreads();

    for (int i = tid; i < nb; i += 1024)
        atomicAdd(&dcnt[records[base + i] >> 16], 1);
    __syncthreads();

    int* pa = sa; int* pb = sb;
    if (tid < 512) pa[tid] = dcnt[tid];
    __syncthreads();
    for (int d = 1; d < 512; d <<= 1) {
        if (tid < 512) pb[tid] = pa[tid] + ((tid >= d) ? pa[tid - d] : 0);
        __syncthreads();
        int* t = pa; pa = pb; pb = t;
    }
    if (tid < 512) {
        int excl = pa[tid] - dcnt[tid];
        dcur[tid] = excl;
        int dst = b * 512 + tid;
        if (dst < NTOT) off[dst] = base + excl;
    }
    if (b == NBKT - 1 && tid == 0) off[NTOT] = NE2;
    __syncthreads();

    if (nb <= CAP) {
        for (int i = tid; i < nb; i += 1024) {
            unsigned int r = records[base + i];
            int p = atomicAdd(&dcur[r >> 16], 1);
            stage[p] = (unsigned short)r;
        }
        __syncthreads();
        for (int i = tid; i < nb; i += 1024) csr[base + i] = stage[i];
    } else {
        for (int i = tid; i < nb; i += 1024) {
            unsigned int r = records[base + i];
            int p = atomicAdd(&dcur[r >> 16], 1);
            csr[base + p] = (unsigned short)r;
        }
    }
}

// ---------------------------------------------------------------------------
// Aggregate (mean), UNFUSED (round-6 structure): 256 thr = 4 free-running
// waves, one wave per dst row, lane owns dims [2l,2l+1], 4 gathers in flight.
// Reads compact stride-128 tables; writes bf16 mean into d_out head halves
// (stride 256): row r<50K (item dst) -> out_item area rows, else out_user.
// ---------------------------------------------------------------------------
__global__ __launch_bounds__(256) void agg2c_kernel(
    const unsigned short* __restrict__ T_user, const unsigned short* __restrict__ T_item,
    const int* __restrict__ off, const unsigned short* __restrict__ csr,
    unsigned short* __restrict__ dout_u16)
{
    int r = (blockIdx.x * blockDim.x + threadIdx.x) >> 6;
    if (r >= NTOT) return;
    const int lane = threadIdx.x & 63;
    const unsigned short* Tg;
    unsigned short* outp;
    if (r < N_ITEM) { Tg = T_user; outp = dout_u16 + (size_t)(N_USER + r) * 256; }
    else            { Tg = T_item; outp = dout_u16 + (size_t)(r - N_ITEM) * 256; }

    const int o0 = off[r], o1 = off[r + 1];
    const int co = lane * 2;
    float ax = 0.f, ay = 0.f;
    int i = o0;
    for (; i + 3 < o1; i += 4) {
        int s0 = csr[i], s1 = csr[i + 1], s2 = csr[i + 2], s3 = csr[i + 3];
        unsigned int w0 = *reinterpret_cast<const unsigned int*>(Tg + (size_t)s0 * 128 + co);
        unsigned int w1 = *reinterpret_cast<const unsigned int*>(Tg + (size_t)s1 * 128 + co);
        unsigned int w2 = *reinterpret_cast<const unsigned int*>(Tg + (size_t)s2 * 128 + co);
        unsigned int w3 = *reinterpret_cast<const unsigned int*>(Tg + (size_t)s3 * 128 + co);
        ax += bf2f((unsigned short)w0) + bf2f((unsigned short)w1)
            + bf2f((unsigned short)w2) + bf2f((unsigned short)w3);
        ay += bf2f((unsigned short)(w0 >> 16)) + bf2f((unsigned short)(w1 >> 16))
            + bf2f((unsigned short)(w2 >> 16)) + bf2f((unsigned short)(w3 >> 16));
    }
    for (; i < o1; ++i) {
        int s = csr[i];
        unsigned int w = *reinterpret_cast<const unsigned int*>(Tg + (size_t)s * 128 + co);
        ax += bf2f((unsigned short)w);
        ay += bf2f((unsigned short)(w >> 16));
    }
    int deg = o1 - o0;
    float sc = (deg > 0) ? 1.0f / (float)deg : 0.0f;
    unsigned int outw = (unsigned int)f2bf(ax * sc) | ((unsigned int)f2bf(ay * sc) << 16);
    *reinterpret_cast<unsigned int*>(outp + co) = outw;
}

// ---------------------------------------------------------------------------
// MFMA finish, UNFUSED (round-6 structure), head from d_out (stride 256,
// in-place row-aliased: bf16[r][256] == fp32[r][128] bytes; wave stores are
// data-dependent on all its loads; waves own disjoint rows), tail from
// compact self table Ts.
// ---------------------------------------------------------------------------
#define NB_FIN 782   // ceil(50000/64)

__global__ __launch_bounds__(256) void finish2c_kernel(
    unsigned short* dout_u16,
    const unsigned short* __restrict__ T_user, const unsigned short* __restrict__ T_item,
    const unsigned short* __restrict__ WfragUI, const unsigned short* __restrict__ WfragIU,
    const float* __restrict__ b_ui, const float* __restrict__ b_iu)
{
    const int b = blockIdx.x;
    const unsigned short *headBase, *Ts, *Wfrag;
    const float* bias;
    float* outp;
    int rowBase;
    if (b < NB_FIN) {
        // item side: head = agg(user feats) stored in out_item area; self = ITEM
        headBase = dout_u16 + (size_t)N_USER * 256;
        Ts = T_item; Wfrag = WfragUI; bias = b_ui;
        outp = reinterpret_cast<float*>(dout_u16) + (size_t)N_USER * 128;
        rowBase = b * 64;
    } else {
        headBase = dout_u16;
        Ts = T_user; Wfrag = WfragIU; bias = b_iu;
        outp = reinterpret_cast<float*>(dout_u16);
        rowBase = (b - NB_FIN) * 64;
    }

    const int tid  = threadIdx.x;
    const int wave = tid >> 6;
    const int lane = tid & 63;
    const int kg   = lane >> 4;
    rowBase += wave * 16;

    int arow = rowBase + (lane & 15);
    int arow_c = (arow < 50000) ? arow : 49999;
    const unsigned short* head_ptr = headBase + (size_t)arow_c * 256 + kg * 8;
    const unsigned short* tail_ptr = Ts + (size_t)arow_c * 128 + kg * 8;

    f32x4 acc[8];
#pragma unroll
    for (int c = 0; c < 8; ++c) acc[c] = (f32x4){0.f, 0.f, 0.f, 0.f};

#pragma unroll
    for (int ks = 0; ks < 8; ++ks) {
        bf16x8 a;
        if (ks < 4) a = *reinterpret_cast<const bf16x8*>(head_ptr + ks * 32);       // agg (Wl)
        else        a = *reinterpret_cast<const bf16x8*>(tail_ptr + (ks - 4) * 32); // self (Wr)
        const unsigned short* bptr = Wfrag + ((size_t)(ks * 8) * 64 + lane) * 8;
#pragma unroll
        for (int c = 0; c < 8; ++c) {
            bf16x8 bb = *reinterpret_cast<const bf16x8*>(bptr + (size_t)c * 512);
            acc[c] = __builtin_amdgcn_mfma_f32_16x16x32_bf16(a, bb, acc[c], 0, 0, 0);
        }
    }

    const int orow0 = rowBase + kg * 4;
    const int ocol  = lane & 15;
#pragma unroll
    for (int c = 0; c < 8; ++c) {
        float bv = bias[c * 16 + ocol];
#pragma unroll
        for (int r = 0; r < 4; ++r) {
            int row = orow0 + r;
            if (row < 50000) outp[(size_t)row * 128 + c * 16 + ocol] = acc[c][r] + bv;
        }
    }
}

// ---------------------------------------------------------------------------
extern "C" void kernel_launch(void* const* d_in, const int* in_sizes, int n_in,
                              void* d_out, int out_size, void* d_ws, size_t ws_size,
                              hipStream_t stream) {
    const int*   user_ids = (const int*)d_in[0];
    const float* item_x   = (const float*)d_in[1];
    const int*   edge_ui  = (const int*)d_in[2];
    const int*   edge_iu  = (const int*)d_in[3];
    const float* user_emb = (const float*)d_in[4];
    const float* W_l_ui   = (const float*)d_in[5];
    const float* W_r_ui   = (const float*)d_in[6];
    const float* b_ui     = (const float*)d_in[7];
    const float* W_l_iu   = (const float*)d_in[8];
    const float* W_r_iu   = (const float*)d_in[9];
    const float* b_iu     = (const float*)d_in[10];

    unsigned short* dout_u16 = (unsigned short*)d_out;

    // Workspace (16B-aligned blocks first)
    unsigned short* WfragUI = (unsigned short*)d_ws;            // 32768 u16
    unsigned short* WfragIU = WfragUI + 32768;                  // 32768 u16
    unsigned short* T_user  = WfragIU + 32768;                  // 50000*128 u16 (12.8MB)
    unsigned short* T_item  = T_user + (size_t)N_USER * 128;    // 12.8MB
    unsigned int*   records = (unsigned int*)(T_item + (size_t)N_ITEM * 128);  // NE2 (6.4MB)
    unsigned short* csr     = (unsigned short*)(records + NE2); // NE2 (3.2MB)
    int* gcnt  = (int*)(csr + NE2);                             // NBKT
    int* bbase = gcnt + NBKT;                                   // NBKT+1
    int* bcur  = bbase + NBKT + 1;                              // NBKT
    int* off   = bcur + NBKT;                                   // NTOT+1

    hipMemsetAsync(gcnt, 0, NBKT * sizeof(int), stream);

    count_kernel<<<CNT_BLOCKS, 256, 0, stream>>>(edge_ui, edge_iu, gcnt);
    bucketscan_kernel<<<1, 256, 0, stream>>>(gcnt, bbase, bcur);
    mega2_kernel<<<PACKA_BLOCKS + PACKW_BLOCKS + SCAT_BLOCKS, 256, 0, stream>>>(
        user_emb, user_ids, item_x, edge_ui, edge_iu,
        W_l_ui, W_r_ui, W_l_iu, W_r_iu,
        T_user, T_item, WfragUI, WfragIU, bcur, records);
    csr_build_kernel<<<NBKT, 1024, 0, stream>>>(records, bbase, csr, off);

    agg2c_kernel<<<(NTOT * 64) / 256, 256, 0, stream>>>(T_user, T_item, off, csr, dout_u16);
    finish2c_kernel<<<2 * NB_FIN, 256, 0, stream>>>(
        dout_u16, T_user, T_item, WfragUI, WfragIU, b_ui, b_iu);
}

// Round 12
// 147.301 us; speedup vs baseline: 1.2129x; 1.1508x over previous
//
#include <hip/hip_runtime.h>

#define N_USER 50000
#define N_ITEM 50000
#define N_EDGE 800000
#define D 128
#define NTOT   100000          // combined dst space: [0,50K)=items, [50K,100K)=users
#define NE2    1600000         // both directions' edges
#define BKT_SH 9               // 512 dsts per bucket
#define NBKT   196             // ceil(NTOT / 512)
#define CAP    12288           // LDS csr staging cap (bucket mean 8192, sigma ~90)

typedef __attribute__((ext_vector_type(8))) short     bf16x8;
typedef __attribute__((ext_vector_type(4))) float     f32x4;
typedef __attribute__((ext_vector_type(4))) unsigned short ushortx4;
typedef __attribute__((ext_vector_type(8))) unsigned short ushortx8;

__device__ __forceinline__ unsigned short f2bf(float f) {
    unsigned int u = __float_as_uint(f);
    unsigned int r = (u + 0x7fffu + ((u >> 16) & 1u)) >> 16;   // RNE
    return (unsigned short)r;
}
__device__ __forceinline__ float bf2f(unsigned short b) {
    return __uint_as_float(((unsigned int)b) << 16);
}

// ---------------------------------------------------------------------------
// MEGA kernel (block-range roles, all 256 thr). pack/packW/count are mutually
// independent -> count's latency hides under pack's copy traffic.
//  [0, 12500)          pack features -> compact bf16 tables T_user/T_item
//  [12500, 12532)      pack W frags (2 x 4096 ids)
//  [12532, 12923)      bucket-count: LDS-binned count of 1.6M edges -> gcnt
// ---------------------------------------------------------------------------
#define PACKA_BLOCKS 12500
#define PACKW_BLOCKS 32
#define CNT_BLOCKS   391   // ceil(NE2 / 4096)

__global__ __launch_bounds__(256) void mega3_kernel(
    const float* __restrict__ user_emb, const int* __restrict__ user_ids,
    const float* __restrict__ item_x,
    const int* __restrict__ edge_ui, const int* __restrict__ edge_iu,
    const float* __restrict__ Wl_ui, const float* __restrict__ Wr_ui,
    const float* __restrict__ Wl_iu, const float* __restrict__ Wr_iu,
    unsigned short* T_user, unsigned short* T_item,
    unsigned short* WfragUI, unsigned short* WfragIU,
    int* __restrict__ gcnt)
{
    const int b = blockIdx.x;
    const int tid = threadIdx.x;

    if (b < PACKA_BLOCKS) {
        int gid = b * 256 + tid;
        int row = gid >> 5;
        int c = (gid & 31) << 2;
        const float* src;
        unsigned short* dst;
        if (row < N_USER) {
            src = user_emb + (size_t)user_ids[row] * D;
            dst = T_user + (size_t)row * 128;
        } else {
            int r = row - N_USER;
            src = item_x + (size_t)r * D;
            dst = T_item + (size_t)r * 128;
        }
        const float4 v = *reinterpret_cast<const float4*>(src + c);
        ushortx4 o;
        o.x = f2bf(v.x); o.y = f2bf(v.y); o.z = f2bf(v.z); o.w = f2bf(v.w);
        *reinterpret_cast<ushortx4*>(dst + c) = o;
    } else if (b < PACKA_BLOCKS + PACKW_BLOCKS) {
        int id = (b - PACKA_BLOCKS) * 256 + tid;   // [0, 8192)
        const float *Wl, *Wr;
        unsigned short* Wf;
        if (id < 4096) { Wl = Wl_ui; Wr = Wr_ui; Wf = WfragUI; }
        else { id -= 4096; Wl = Wl_iu; Wr = Wr_iu; Wf = WfragIU; }
        int lane = id & 63;
        int c    = (id >> 6) & 7;
        int ks   = id >> 9;
        int col  = c * 16 + (lane & 15);
        int k0   = ks * 32 + (lane >> 4) * 8;
        ushortx8 o;
#pragma unroll
        for (int i = 0; i < 8; ++i) {
            int k = k0 + i;
            float f = (k < D) ? Wl[(size_t)k * D + col] : Wr[(size_t)(k - D) * D + col];
            o[i] = f2bf(f);
        }
        *reinterpret_cast<ushortx8*>(Wf + (size_t)id * 8) = o;
    } else {
        __shared__ int bcnt[NBKT];
        for (int i = tid; i < NBKT; i += 256) bcnt[i] = 0;
        __syncthreads();
        int e0 = (b - PACKA_BLOCKS - PACKW_BLOCKS) * 4096;
#pragma unroll
        for (int j = 0; j < 16; ++j) {
            int e = e0 + j * 256 + tid;
            if (e < NE2) {
                int d = (e < N_EDGE) ? edge_ui[N_EDGE + e]
                                     : (N_ITEM + edge_iu[N_EDGE + (e - N_EDGE)]);
                atomicAdd(&bcnt[d >> BKT_SH], 1);
            }
        }
        __syncthreads();
        for (int i = tid; i < NBKT; i += 256)
            if (bcnt[i]) atomicAdd(&gcnt[i], bcnt[i]);
    }
}

// ---------------------------------------------------------------------------
// Scan 196 bucket counts -> bucket bases; init bucket cursors.
// ---------------------------------------------------------------------------
__global__ __launch_bounds__(256) void bucketscan_kernel(
    const int* __restrict__ gcnt, int* __restrict__ bbase, int* __restrict__ bcur)
{
    __shared__ int s[256];
    int tid = threadIdx.x;
    int v = (tid < NBKT) ? gcnt[tid] : 0;
    s[tid] = v;
    __syncthreads();
    for (int d = 1; d < 256; d <<= 1) {
        int t = (tid >= d) ? s[tid - d] : 0;
        __syncthreads();
        s[tid] += t;
        __syncthreads();
    }
    if (tid < NBKT) {
        int base = s[tid] - v;     // exclusive
        bbase[tid] = base;
        bcur[tid]  = base;
    }
    if (tid == NBKT - 1) bbase[NBKT] = s[tid];
}

// ---------------------------------------------------------------------------
// Scatter records into bucket-segmented array. Record = src16 | dstlow9<<16.
// Rank captured from the pass-1 count atomic; pass 2 reserves one chunk per
// (block,bucket); final writes are atomic-free: pos = chunk base + rank.
// ---------------------------------------------------------------------------
#define B2_BLOCKS 196   // ceil(NE2 / 8192)

__global__ __launch_bounds__(1024) void scatter_records_kernel(
    const int* __restrict__ edge_ui, const int* __restrict__ edge_iu,
    int* __restrict__ bcur, unsigned int* __restrict__ records)
{
    __shared__ int bcnt[NBKT];
    __shared__ int bpos[NBKT];
    const int tid = threadIdx.x;
    for (int i = tid; i < NBKT; i += 1024) bcnt[i] = 0;
    __syncthreads();

    const int e0 = blockIdx.x * 8192;
    unsigned int rec[8];
    int bkt[8], rnk[8];
#pragma unroll
    for (int j = 0; j < 8; ++j) {
        int e = e0 + j * 1024 + tid;
        bkt[j] = -1;
        if (e < NE2) {
            int s, d;
            if (e < N_EDGE) { s = edge_ui[e]; d = edge_ui[N_EDGE + e]; }
            else { int f = e - N_EDGE; s = edge_iu[f]; d = N_ITEM + edge_iu[N_EDGE + f]; }
            bkt[j] = d >> BKT_SH;
            rec[j] = (unsigned int)s | ((unsigned int)(d & 511) << 16);
            rnk[j] = atomicAdd(&bcnt[bkt[j]], 1);
        }
    }
    __syncthreads();
    for (int i = tid; i < NBKT; i += 1024) {
        int c = bcnt[i];
        bpos[i] = c ? atomicAdd(&bcur[i], c) : 0;
    }
    __syncthreads();
#pragma unroll
    for (int j = 0; j < 8; ++j) {
        if (bkt[j] >= 0) records[bpos[bkt[j]] + rnk[j]] = rec[j];
    }
}

// ---------------------------------------------------------------------------
// Per-bucket CSR build: LDS counting-sort by dst within the bucket; emits off[].
// ---------------------------------------------------------------------------
__global__ __launch_bounds__(1024) void csr_build_kernel(
    const unsigned int* __restrict__ records, const int* __restrict__ bbase,
    unsigned short* __restrict__ csr, int* __restrict__ off)
{
    __shared__ int dcnt[512];
    __shared__ int sa[512], sb[512];
    __shared__ int dcur[512];
    __shared__ unsigned short stage[CAP];

    const int b    = blockIdx.x;
    const int tid  = threadIdx.x;
    const int base = bbase[b];
    const int nb   = bbase[b + 1] - base;

    if (tid < 512) dcnt[tid] = 0;
    __syncthreads();

    for (int i = tid; i < nb; i += 1024)
        atomicAdd(&dcnt[records[base + i] >> 16], 1);
    __syncthreads();

    int* pa = sa; int* pb = sb;
    if (tid < 512) pa[tid] = dcnt[tid];
    __syncthreads();
    for (int d = 1; d < 512; d <<= 1) {
        if (tid < 512) pb[tid] = pa[tid] + ((tid >= d) ? pa[tid - d] : 0);
        __syncthreads();
        int* t = pa; pa = pb; pb = t;
    }
    if (tid < 512) {
        int excl = pa[tid] - dcnt[tid];
        dcur[tid] = excl;
        int dst = b * 512 + tid;
        if (dst < NTOT) off[dst] = base + excl;
    }
    if (b == NBKT - 1 && tid == 0) off[NTOT] = NE2;
    __syncthreads();

    if (nb <= CAP) {
        for (int i = tid; i < nb; i += 1024) {
            unsigned int r = records[base + i];
            int p = atomicAdd(&dcur[r >> 16], 1);
            stage[p] = (unsigned short)r;
        }
        __syncthreads();
        for (int i = tid; i < nb; i += 1024) csr[base + i] = stage[i];
    } else {
        for (int i = tid; i < nb; i += 1024) {
            unsigned int r = records[base + i];
            int p = atomicAdd(&dcur[r >> 16], 1);
            csr[base + p] = (unsigned short)r;
        }
    }
}

// ---------------------------------------------------------------------------
// Aggregate (mean), 8-deep unrolled gather: 256 thr = 4 free-running waves,
// one wave per dst row, lane owns dims [2l,2l+1], 8 gathers in flight.
// Writes bf16 mean into d_out head halves (stride 256).
// ---------------------------------------------------------------------------
__global__ __launch_bounds__(256) void agg2c_kernel(
    const unsigned short* __restrict__ T_user, const unsigned short* __restrict__ T_item,
    const int* __restrict__ off, const unsigned short* __restrict__ csr,
    unsigned short* __restrict__ dout_u16)
{
    int r = (blockIdx.x * blockDim.x + threadIdx.x) >> 6;
    if (r >= NTOT) return;
    const int lane = threadIdx.x & 63;
    const unsigned short* Tg;
    unsigned short* outp;
    if (r < N_ITEM) { Tg = T_user; outp = dout_u16 + (size_t)(N_USER + r) * 256; }
    else            { Tg = T_item; outp = dout_u16 + (size_t)(r - N_ITEM) * 256; }

    const int o0 = off[r], o1 = off[r + 1];
    const int co = lane * 2;
    float ax = 0.f, ay = 0.f;
    int i = o0;
    for (; i + 7 < o1; i += 8) {
        int s0 = csr[i],     s1 = csr[i + 1], s2 = csr[i + 2], s3 = csr[i + 3];
        int s4 = csr[i + 4], s5 = csr[i + 5], s6 = csr[i + 6], s7 = csr[i + 7];
        unsigned int w0 = *reinterpret_cast<const unsigned int*>(Tg + (size_t)s0 * 128 + co);
        unsigned int w1 = *reinterpret_cast<const unsigned int*>(Tg + (size_t)s1 * 128 + co);
        unsigned int w2 = *reinterpret_cast<const unsigned int*>(Tg + (size_t)s2 * 128 + co);
        unsigned int w3 = *reinterpret_cast<const unsigned int*>(Tg + (size_t)s3 * 128 + co);
        unsigned int w4 = *reinterpret_cast<const unsigned int*>(Tg + (size_t)s4 * 128 + co);
        unsigned int w5 = *reinterpret_cast<const unsigned int*>(Tg + (size_t)s5 * 128 + co);
        unsigned int w6 = *reinterpret_cast<const unsigned int*>(Tg + (size_t)s6 * 128 + co);
        unsigned int w7 = *reinterpret_cast<const unsigned int*>(Tg + (size_t)s7 * 128 + co);
        ax += bf2f((unsigned short)w0) + bf2f((unsigned short)w1)
            + bf2f((unsigned short)w2) + bf2f((unsigned short)w3)
            + bf2f((unsigned short)w4) + bf2f((unsigned short)w5)
            + bf2f((unsigned short)w6) + bf2f((unsigned short)w7);
        ay += bf2f((unsigned short)(w0 >> 16)) + bf2f((unsigned short)(w1 >> 16))
            + bf2f((unsigned short)(w2 >> 16)) + bf2f((unsigned short)(w3 >> 16))
            + bf2f((unsigned short)(w4 >> 16)) + bf2f((unsigned short)(w5 >> 16))
            + bf2f((unsigned short)(w6 >> 16)) + bf2f((unsigned short)(w7 >> 16));
    }
    for (; i + 3 < o1; i += 4) {
        int s0 = csr[i], s1 = csr[i + 1], s2 = csr[i + 2], s3 = csr[i + 3];
        unsigned int w0 = *reinterpret_cast<const unsigned int*>(Tg + (size_t)s0 * 128 + co);
        unsigned int w1 = *reinterpret_cast<const unsigned int*>(Tg + (size_t)s1 * 128 + co);
        unsigned int w2 = *reinterpret_cast<const unsigned int*>(Tg + (size_t)s2 * 128 + co);
        unsigned int w3 = *reinterpret_cast<const unsigned int*>(Tg + (size_t)s3 * 128 + co);
        ax += bf2f((unsigned short)w0) + bf2f((unsigned short)w1)
            + bf2f((unsigned short)w2) + bf2f((unsigned short)w3);
        ay += bf2f((unsigned short)(w0 >> 16)) + bf2f((unsigned short)(w1 >> 16))
            + bf2f((unsigned short)(w2 >> 16)) + bf2f((unsigned short)(w3 >> 16));
    }
    for (; i < o1; ++i) {
        int s = csr[i];
        unsigned int w = *reinterpret_cast<const unsigned int*>(Tg + (size_t)s * 128 + co);
        ax += bf2f((unsigned short)w);
        ay += bf2f((unsigned short)(w >> 16));
    }
    int deg = o1 - o0;
    float sc = (deg > 0) ? 1.0f / (float)deg : 0.0f;
    unsigned int outw = (unsigned int)f2bf(ax * sc) | ((unsigned int)f2bf(ay * sc) << 16);
    *reinterpret_cast<unsigned int*>(outp + co) = outw;
}

// ---------------------------------------------------------------------------
// MFMA finish (round-6 structure), head from d_out (stride 256, in-place
// row-aliased: bf16[r][256] == fp32[r][128] bytes; wave stores depend on all
// its loads; waves own disjoint rows), tail from compact self table Ts.
// ---------------------------------------------------------------------------
#define NB_FIN 782   // ceil(50000/64)

__global__ __launch_bounds__(256) void finish2c_kernel(
    unsigned short* dout_u16,
    const unsigned short* __restrict__ T_user, const unsigned short* __restrict__ T_item,
    const unsigned short* __restrict__ WfragUI, const unsigned short* __restrict__ WfragIU,
    const float* __restrict__ b_ui, const float* __restrict__ b_iu)
{
    const int b = blockIdx.x;
    const unsigned short *headBase, *Ts, *Wfrag;
    const float* bias;
    float* outp;
    int rowBase;
    if (b < NB_FIN) {
        headBase = dout_u16 + (size_t)N_USER * 256;
        Ts = T_item; Wfrag = WfragUI; bias = b_ui;
        outp = reinterpret_cast<float*>(dout_u16) + (size_t)N_USER * 128;
        rowBase = b * 64;
    } else {
        headBase = dout_u16;
        Ts = T_user; Wfrag = WfragIU; bias = b_iu;
        outp = reinterpret_cast<float*>(dout_u16);
        rowBase = (b - NB_FIN) * 64;
    }

    const int tid  = threadIdx.x;
    const int wave = tid >> 6;
    const int lane = tid & 63;
    const int kg   = lane >> 4;
    rowBase += wave * 16;

    int arow = rowBase + (lane & 15);
    int arow_c = (arow < 50000) ? arow : 49999;
    const unsigned short* head_ptr = headBase + (size_t)arow_c * 256 + kg * 8;
    const unsigned short* tail_ptr = Ts + (size_t)arow_c * 128 + kg * 8;

    f32x4 acc[8];
#pragma unroll
    for (int c = 0; c < 8; ++c) acc[c] = (f32x4){0.f, 0.f, 0.f, 0.f};

#pragma unroll
    for (int ks = 0; ks < 8; ++ks) {
        bf16x8 a;
        if (ks < 4) a = *reinterpret_cast<const bf16x8*>(head_ptr + ks * 32);       // agg (Wl)
        else        a = *reinterpret_cast<const bf16x8*>(tail_ptr + (ks - 4) * 32); // self (Wr)
        const unsigned short* bptr = Wfrag + ((size_t)(ks * 8) * 64 + lane) * 8;
#pragma unroll
        for (int c = 0; c < 8; ++c) {
            bf16x8 bb = *reinterpret_cast<const bf16x8*>(bptr + (size_t)c * 512);
            acc[c] = __builtin_amdgcn_mfma_f32_16x16x32_bf16(a, bb, acc[c], 0, 0, 0);
        }
    }

    const int orow0 = rowBase + kg * 4;
    const int ocol  = lane & 15;
#pragma unroll
    for (int c = 0; c < 8; ++c) {
        float bv = bias[c * 16 + ocol];
#pragma unroll
        for (int r = 0; r < 4; ++r) {
            int row = orow0 + r;
            if (row < 50000) outp[(size_t)row * 128 + c * 16 + ocol] = acc[c][r] + bv;
        }
    }
}

// ---------------------------------------------------------------------------
extern "C" void kernel_launch(void* const* d_in, const int* in_sizes, int n_in,
                              void* d_out, int out_size, void* d_ws, size_t ws_size,
                              hipStream_t stream) {
    const int*   user_ids = (const int*)d_in[0];
    const float* item_x   = (const float*)d_in[1];
    const int*   edge_ui  = (const int*)d_in[2];
    const int*   edge_iu  = (const int*)d_in[3];
    const float* user_emb = (const float*)d_in[4];
    const float* W_l_ui   = (const float*)d_in[5];
    const float* W_r_ui   = (const float*)d_in[6];
    const float* b_ui     = (const float*)d_in[7];
    const float* W_l_iu   = (const float*)d_in[8];
    const float* W_r_iu   = (const float*)d_in[9];
    const float* b_iu     = (const float*)d_in[10];

    unsigned short* dout_u16 = (unsigned short*)d_out;

    // Workspace (16B-aligned blocks first)
    unsigned short* WfragUI = (unsigned short*)d_ws;            // 32768 u16
    unsigned short* WfragIU = WfragUI + 32768;                  // 32768 u16
    unsigned short* T_user  = WfragIU + 32768;                  // 50000*128 u16 (12.8MB)
    unsigned short* T_item  = T_user + (size_t)N_USER * 128;    // 12.8MB
    unsigned int*   records = (unsigned int*)(T_item + (size_t)N_ITEM * 128);  // NE2 (6.4MB)
    unsigned short* csr     = (unsigned short*)(records + NE2); // NE2 (3.2MB)
    int* gcnt  = (int*)(csr + NE2);                             // NBKT
    int* bbase = gcnt + NBKT;                                   // NBKT+1
    int* bcur  = bbase + NBKT + 1;                              // NBKT
    int* off   = bcur + NBKT;                                   // NTOT+1

    hipMemsetAsync(gcnt, 0, NBKT * sizeof(int), stream);

    mega3_kernel<<<PACKA_BLOCKS + PACKW_BLOCKS + CNT_BLOCKS, 256, 0, stream>>>(
        user_emb, user_ids, item_x, edge_ui, edge_iu,
        W_l_ui, W_r_ui, W_l_iu, W_r_iu,
        T_user, T_item, WfragUI, WfragIU, gcnt);
    bucketscan_kernel<<<1, 256, 0, stream>>>(gcnt, bbase, bcur);
    scatter_records_kernel<<<B2_BLOCKS, 1024, 0, stream>>>(edge_ui, edge_iu, bcur, records);
    csr_build_kernel<<<NBKT, 1024, 0, stream>>>(records, bbase, csr, off);

    agg2c_kernel<<<(NTOT * 64) / 256, 256, 0, stream>>>(T_user, T_item, off, csr, dout_u16);
    finish2c_kernel<<<2 * NB_FIN, 256, 0, stream>>>(
        dout_u16, T_user, T_item, WfragUI, WfragIU, b_ui, b_iu);
}